// Round 7
// baseline (199.758 us; speedup 1.0000x reference)
//
#include <hip/hip_runtime.h>

typedef short short8 __attribute__((ext_vector_type(8)));
typedef float f32x4 __attribute__((ext_vector_type(4)));
typedef float f32x16 __attribute__((ext_vector_type(16)));

#define SQ   1024
#define DIN  768
#define NH   12
#define DH   64
#define SCL2 0.1803368801111243f   /* 0.125 * log2(e) */

static __device__ __forceinline__ ushort f2bf(float f) {
  union { float f; unsigned u; } v; v.f = f;
  unsigned u = v.u;
  unsigned r = (u + 0x7FFFu + ((u >> 16) & 1u)) >> 16;
  return (ushort)r;
}
static __device__ __forceinline__ unsigned pk2(float a, float b) {
  return (unsigned)f2bf(a) | ((unsigned)f2bf(b) << 16);
}

static __device__ __forceinline__ void gload_lds16(const ushort* g, ushort* l) {
  __builtin_amdgcn_global_load_lds(
      (const __attribute__((address_space(1))) unsigned*)(g),
      (__attribute__((address_space(3))) unsigned*)(l),
      16, 0, 0);
}

// ---------------------------------------------------------------- prep: x -> bf16
__global__ __launch_bounds__(256) void k_convert_x(const float* __restrict__ x,
                                                   ushort* __restrict__ xb) {
  int i = (blockIdx.x * 256 + threadIdx.x) * 4;
  float4 v = *reinterpret_cast<const float4*>(x + i);
  ushort4 o;
  o.x = f2bf(v.x); o.y = f2bf(v.y); o.z = f2bf(v.z); o.w = f2bf(v.w);
  *reinterpret_cast<ushort4*>(xb + i) = o;
}

// ------------------------------- prep: W[h][d][e] -> Wt[(m*12+h)*64+e][d] bf16 (B^T)
__global__ __launch_bounds__(256) void k_prep_w(const float* __restrict__ Wq,
                                                const float* __restrict__ Wk,
                                                const float* __restrict__ Wv,
                                                ushort* __restrict__ wt) {
  __shared__ ushort tile[64][65];
  const int mh = blockIdx.x;            // m*12 + h
  const int m = mh / 12, h = mh % 12;
  const int d0 = blockIdx.y * 64;
  const float* W = (m == 0 ? Wq : (m == 1 ? Wk : Wv)) + h * DIN * DH;
  ushort* outp = wt + (size_t)mh * DH * DIN;
  #pragma unroll
  for (int p = 0; p < 16; ++p) {
    int idx = p * 256 + threadIdx.x;
    int d = idx >> 6, e = idx & 63;
    tile[d][e] = f2bf(W[(d0 + d) * DH + e]);
  }
  __syncthreads();
  #pragma unroll
  for (int p = 0; p < 16; ++p) {
    int idx = p * 256 + threadIdx.x;
    int e = idx >> 6, d = idx & 63;
    outp[e * DIN + d0 + d] = tile[d][e];
  }
}

// ------------------------------------------------- QKV projection as ONE GEMM
// C[8192 x 2304] = xb[8192 x 768] * wt^T. 128x128 tile, BK=32, 4 waves (2x2) each 64x64.
// Depth-2 prefetch: 3 LDS buffers, counted vmcnt(4) + raw s_barrier (no vmcnt(0) drain
// in steady state). Bank-conflict-free swizzle f(r) = (r&3)^((r>>2)&3) on both sides.
__global__ __launch_bounds__(256) void k_proj(const ushort* __restrict__ xb,
                                              const ushort* __restrict__ wt,
                                              ushort* __restrict__ qo,
                                              ushort* __restrict__ ko,
                                              ushort* __restrict__ vto) {
  __shared__ __align__(16) ushort Ab[3][128][32];   // 3 x 8 KB
  __shared__ __align__(16) ushort Bb[3][128][32];   // 3 x 8 KB  (total 48 KB)

  const int brow = blockIdx.x * 128;
  const int bn   = blockIdx.y * 128;
  const int w    = threadIdx.x >> 6, lane = threadIdx.x & 63;
  const int lr   = lane & 15, lg = lane >> 4;
  const int wm   = w >> 1, wn = w & 1;

  // staging: thread covers LDS row srow (64 B rows), 16B slot (tid&3), per half-tile.
  // source slot pre-swizzled by f(row) = (row&3)^((row>>2)&3)  [same f for row+64]
  const int srow  = threadIdx.x >> 2;
  const int sslot = (threadIdx.x & 3) ^ (srow & 3) ^ ((srow >> 2) & 3);
  const ushort* gA = xb + (size_t)(brow + srow) * DIN + sslot * 8;
  const ushort* gB = wt + (size_t)(bn   + srow) * DIN + sslot * 8;

  f32x4 acc[4][4];
  #pragma unroll
  for (int i = 0; i < 4; ++i)
    #pragma unroll
    for (int j = 0; j < 4; ++j) acc[i][j] = (f32x4){0.f, 0.f, 0.f, 0.f};

  // read-side swizzle: row = (wm|wn)*64 + mi*16 + lr -> f(row) dep. on lr only
  const int fr   = (lr & 3) ^ ((lr >> 2) & 3);
  const int aoff = (lg ^ fr) * 8;

#define STAGE(bi, tt) do {                                                \
    const int k0_ = (tt) * 32;                                            \
    ushort* la_ = &Ab[bi][0][0] + threadIdx.x * 8;                        \
    ushort* lb_ = &Bb[bi][0][0] + threadIdx.x * 8;                        \
    gload_lds16(gA + k0_,            la_);                                \
    gload_lds16(gA + k0_ + 64 * DIN, la_ + 2048);                         \
    gload_lds16(gB + k0_,            lb_);                                \
    gload_lds16(gB + k0_ + 64 * DIN, lb_ + 2048);                         \
  } while (0)

  STAGE(0, 0);
  STAGE(1, 1);

  int cur = 0;
  #pragma unroll 1
  for (int t = 0; t < 24; ++t) {
    // wait for tile t's 4 loads (issued 2 iters ago); keep newer tiles in flight
    if (t < 23) {
      asm volatile("s_waitcnt vmcnt(4)" ::: "memory");
    } else {
      asm volatile("s_waitcnt vmcnt(0)" ::: "memory");
    }
    __builtin_amdgcn_sched_barrier(0);
    __builtin_amdgcn_s_barrier();
    __builtin_amdgcn_sched_barrier(0);
    if (t + 2 < 24) {
      int nb = cur + 2; if (nb >= 3) nb -= 3;
      STAGE(nb, t + 2);
    }
    short8 a[4], b[4];
    #pragma unroll
    for (int mi = 0; mi < 4; ++mi)
      a[mi] = *reinterpret_cast<const short8*>(&Ab[cur][wm * 64 + mi * 16 + lr][aoff]);
    #pragma unroll
    for (int ci = 0; ci < 4; ++ci)
      b[ci] = *reinterpret_cast<const short8*>(&Bb[cur][wn * 64 + ci * 16 + lr][aoff]);
    #pragma unroll
    for (int mi = 0; mi < 4; ++mi)
      #pragma unroll
      for (int ci = 0; ci < 4; ++ci)
        acc[mi][ci] = __builtin_amdgcn_mfma_f32_16x16x32_bf16(a[mi], b[ci], acc[mi][ci], 0, 0, 0);
    cur += 1; if (cur >= 3) cur = 0;
  }
#undef STAGE

  const int mh = (bn + wn * 64) >> 6;
  const int m = mh / 12, h = mh % 12;
  const int lgq = lane >> 4;
  #pragma unroll
  for (int mi = 0; mi < 4; ++mi)
    #pragma unroll
    for (int ci = 0; ci < 4; ++ci)
      #pragma unroll
      for (int r = 0; r < 4; ++r) {
        int rg = brow + wm * 64 + mi * 16 + lgq * 4 + r;
        int b_ = rg >> 10, sl = rg & 1023;
        int bh = b_ * 12 + h;
        int e  = ci * 16 + lr;
        ushort val = f2bf(acc[mi][ci][r]);
        if (m == 2) {
          vto[((size_t)bh * DH + e) * SQ + sl] = val;
        } else {
          ushort* dst = (m == 0) ? qo : ko;
          dst[((size_t)bh * SQ + sl) * DH + e] = val;
        }
      }
}

// ------------------------------------------------- fused causal flash attention
// m214-style: swapped QK^T (S^T = mfma32(K, Q)), in-register softmax + in-register
// P->PV via pack + shfl_xor(32)+select. 4 waves x 32 q-rows; KVBLK=64; K/V^T in LDS
// (double-buffered, global_load_lds w=16, both-sides XOR swizzle). No P LDS.
// grid: 768 flat, nonlinear (qt,bh) remap to break per-CU same-qt alignment.
__global__ __launch_bounds__(256, 3) void k_attn(const ushort* __restrict__ qi,
                                                 const ushort* __restrict__ ki,
                                                 const ushort* __restrict__ vti,
                                                 float* __restrict__ out) {
  __shared__ __align__(16) ushort Kb[2][64 * 64];
  __shared__ __align__(16) ushort Vb[2][64 * 64];

  const int f = blockIdx.x;
  const int g = f >> 8, r_ = f & 255;
  const int qt = ((r_ & 7) + g * 3) & 7;        // bijective, breaks 256-stride alignment
  const int bh = g * 32 + (r_ >> 3);
  const int b = bh / 12, h = bh % 12;
  const int w = threadIdx.x >> 6, lane = threadIdx.x & 63;
  const int ql = lane & 31, hi = lane >> 5;
  const int q0 = qt * 128 + w * 32;
  const int nt = (q0 >> 6) + 1;                 // this wave's kv-tile count
  const int ntmax = 2 * qt + 2;                 // block's kv-tile count
  const ushort* qb = qi  + (size_t)bh * SQ * DH;
  const ushort* kb = ki  + (size_t)bh * SQ * DH;
  const ushort* vb = vti + (size_t)bh * DH * SQ;

  // Q as B-fragments: lane holds Q[q0+ql][d = m*16 + hi*8 + j]
  short8 qf[4];
  #pragma unroll
  for (int m = 0; m < 4; ++m)
    qf[m] = *reinterpret_cast<const short8*>(qb + (size_t)(q0 + ql) * DH + m * 16 + hi * 8);

  f32x16 o0, o1;                                 // O[e-half][reg->q]; col e = eh*32+ql
  #pragma unroll
  for (int r = 0; r < 16; ++r) { o0[r] = 0.f; o1[r] = 0.f; }
  float m_run = -1e30f, l_run = 0.f;

#define STAGE(bufi, tt) do {                                                                   \
    const int kv0_ = (tt) * 64;                                                                \
    const int t0 = threadIdx.x, t1 = threadIdx.x + 256;                                        \
    gload_lds16(kb + (size_t)(kv0_ + (t0 >> 3)) * DH + (((t0 & 7) ^ ((t0 >> 3) & 7)) * 8),     \
                &Kb[bufi][0] + t0 * 8);                                                        \
    gload_lds16(kb + (size_t)(kv0_ + (t1 >> 3)) * DH + (((t1 & 7) ^ ((t1 >> 3) & 7)) * 8),     \
                &Kb[bufi][0] + t1 * 8);                                                        \
    gload_lds16(vb + (size_t)(t0 >> 3) * SQ + kv0_ + (((t0 & 7) ^ ((t0 >> 3) & 7)) * 8),       \
                &Vb[bufi][0] + t0 * 8);                                                        \
    gload_lds16(vb + (size_t)(t1 >> 3) * SQ + kv0_ + (((t1 & 7) ^ ((t1 >> 3) & 7)) * 8),       \
                &Vb[bufi][0] + t1 * 8);                                                        \
  } while (0)

  STAGE(0, 0);
  __syncthreads();

  int cur = 0;
  #pragma unroll 1
  for (int t = 0; t < ntmax; ++t) {
    if (t + 1 < ntmax) STAGE(cur ^ 1, t + 1);

    if (t < nt) {
      const int kv0 = t * 64;
      const ushort* Kc = &Kb[cur][0];
      const ushort* Vc = &Vb[cur][0];

      // ---- S^T = K Q^T : two 32x32 subtiles (kv 0-31, 32-63), k=4 chunks of 16
      f32x16 s0, s1;
      #pragma unroll
      for (int r = 0; r < 16; ++r) { s0[r] = 0.f; s1[r] = 0.f; }
      #pragma unroll
      for (int m = 0; m < 4; ++m) {
        short8 kf = *reinterpret_cast<const short8*>(Kc + ql * 64 + ((2 * m + hi) ^ (ql & 7)) * 8);
        s0 = __builtin_amdgcn_mfma_f32_32x32x16_bf16(kf, qf[m], s0, 0, 0, 0);
      }
      #pragma unroll
      for (int m = 0; m < 4; ++m) {
        short8 kf = *reinterpret_cast<const short8*>(Kc + (32 + ql) * 64 + ((2 * m + hi) ^ (ql & 7)) * 8);
        s1 = __builtin_amdgcn_mfma_f32_32x32x16_bf16(kf, qf[m], s1, 0, 0, 0);
      }

      // ---- causal mask (diag tile only): kv = kv0 + sub*32 + (r&3)+8*(r>>2)+4*hi
      if (t == nt - 1) {
        const int qg = q0 + ql;
        #pragma unroll
        for (int r = 0; r < 16; ++r) {
          int kvl = (r & 3) + 8 * (r >> 2) + 4 * hi;
          if (kv0 + kvl      > qg) s0[r] = -1e30f;
          if (kv0 + 32 + kvl > qg) s1[r] = -1e30f;
        }
      }

      // ---- online softmax, in-lane (q = ql) + one cross-half shfl
      float mt = s0[0];
      #pragma unroll
      for (int r = 1; r < 16; ++r) mt = fmaxf(mt, s0[r]);
      #pragma unroll
      for (int r = 0; r < 16; ++r) mt = fmaxf(mt, s1[r]);
      mt = fmaxf(mt, __shfl_xor(mt, 32));
      if (__any(mt > m_run + 40.0f)) {           // defer-rescale (raw-units THR = 5/0.125)
        float mnew = fmaxf(m_run, mt);
        float corr = exp2f((m_run - mnew) * SCL2);
        l_run *= corr; m_run = mnew;
        #pragma unroll
        for (int r = 0; r < 16; ++r) {
          float cr = __shfl(corr, (r & 3) + 8 * (r >> 2) + 4 * hi);
          o0[r] *= cr; o1[r] *= cr;
        }
      }
      float ts = 0.f;
      #pragma unroll
      for (int r = 0; r < 16; ++r) {
        s0[r] = exp2f((s0[r] - m_run) * SCL2); ts += s0[r];
        s1[r] = exp2f((s1[r] - m_run) * SCL2); ts += s1[r];
      }
      ts += __shfl_xor(ts, 32);
      l_run += ts;

      // ---- P -> A-fragments in-register, then O += P V
      // chunk kc covers kv [kc*16, kc*16+16); lane needs P[q=ql][kv=kc*16+hi*8+j]
#define PV_CHUNK(SV, CC, KC) do {                                                              \
        unsigned wa = pk2(SV[(CC) * 8 + 0], SV[(CC) * 8 + 1]);                                 \
        unsigned wb = pk2(SV[(CC) * 8 + 2], SV[(CC) * 8 + 3]);                                 \
        unsigned wc = pk2(SV[(CC) * 8 + 4], SV[(CC) * 8 + 5]);                                 \
        unsigned wd = pk2(SV[(CC) * 8 + 6], SV[(CC) * 8 + 7]);                                 \
        unsigned xa = __shfl_xor(wa, 32), xb2 = __shfl_xor(wb, 32);                            \
        unsigned xc = __shfl_xor(wc, 32), xd = __shfl_xor(wd, 32);                             \
        uint4 pw;                                                                              \
        pw.x = hi ? xc : wa;  pw.y = hi ? xd : wb;                                             \
        pw.z = hi ? wc : xa;  pw.w = hi ? wd : xb2;                                            \
        short8 pa = *reinterpret_cast<short8*>(&pw);                                           \
        short8 vf0 = *reinterpret_cast<const short8*>(Vc + ql * 64 +                           \
                       ((2 * (KC) + hi) ^ (ql & 7)) * 8);                                      \
        o0 = __builtin_amdgcn_mfma_f32_32x32x16_bf16(pa, vf0, o0, 0, 0, 0);                    \
        short8 vf1 = *reinterpret_cast<const short8*>(Vc + (32 + ql) * 64 +                    \
                       ((2 * (KC) + hi) ^ (ql & 7)) * 8);                                      \
        o1 = __builtin_amdgcn_mfma_f32_32x32x16_bf16(pa, vf1, o1, 0, 0, 0);                    \
      } while (0)

      PV_CHUNK(s0, 0, 0);
      PV_CHUNK(s0, 1, 1);
      PV_CHUNK(s1, 0, 2);
      PV_CHUNK(s1, 1, 3);
#undef PV_CHUNK
    }

    __syncthreads();
    cur ^= 1;
  }
#undef STAGE

  // ---- epilogue: O[q][e] / l[q], q = q0 + (r&3)+8*(r>>2)+4*hi, e = eh*32+ql
  float rl = 1.0f / l_run;
  #pragma unroll
  for (int r = 0; r < 16; ++r) {
    int base = (r & 3) + 8 * (r >> 2) + 4 * hi;
    float sc_ = __shfl(rl, base);
    int qg = q0 + base;
    float* op = out + ((size_t)b * SQ + qg) * (NH * DH) + h * DH;
    op[ql]      = o0[r] * sc_;
    op[32 + ql] = o1[r] * sc_;
  }
}

extern "C" void kernel_launch(void* const* d_in, const int* in_sizes, int n_in,
                              void* d_out, int out_size, void* d_ws, size_t ws_size,
                              hipStream_t stream) {
  const float* x  = (const float*)d_in[0];
  const float* Wq = (const float*)d_in[1];
  const float* Wk = (const float*)d_in[2];
  const float* Wv = (const float*)d_in[3];
  float* out = (float*)d_out;

  char* ws = (char*)d_ws;
  ushort* xb = (ushort*)(ws);
  ushort* wt = (ushort*)(ws + 12582912);
  ushort* q  = (ushort*)(ws + 16121856);
  ushort* k  = (ushort*)(ws + 28704768);
  ushort* vt = (ushort*)(ws + 41287680);

  k_convert_x<<<6144, 256, 0, stream>>>(x, xb);
  k_prep_w<<<dim3(36, 12), 256, 0, stream>>>(Wq, Wk, Wv, wt);
  k_proj<<<dim3(64, 18), 256, 0, stream>>>(xb, wt, q, k, vt);
  k_attn<<<768, 256, 0, stream>>>(q, k, vt, out);
}

// Round 8
// 177.658 us; speedup vs baseline: 1.1244x; 1.1244x over previous
//
#include <hip/hip_runtime.h>

typedef short short8 __attribute__((ext_vector_type(8)));
typedef float f32x4 __attribute__((ext_vector_type(4)));
typedef float f32x16 __attribute__((ext_vector_type(16)));

#define SQ   1024
#define DIN  768
#define NH   12
#define DH   64
#define SCL2 0.1803368801111243f   /* 0.125 * log2(e) */

static __device__ __forceinline__ ushort f2bf(float f) {
  union { float f; unsigned u; } v; v.f = f;
  unsigned u = v.u;
  unsigned r = (u + 0x7FFFu + ((u >> 16) & 1u)) >> 16;
  return (ushort)r;
}
static __device__ __forceinline__ unsigned pk2(float a, float b) {
  return (unsigned)f2bf(a) | ((unsigned)f2bf(b) << 16);
}

static __device__ __forceinline__ void gload_lds16(const ushort* g, ushort* l) {
  __builtin_amdgcn_global_load_lds(
      (const __attribute__((address_space(1))) unsigned*)(g),
      (__attribute__((address_space(3))) unsigned*)(l),
      16, 0, 0);
}

// ---------------------------------------------------------------- prep: x -> bf16
__global__ __launch_bounds__(256) void k_convert_x(const float* __restrict__ x,
                                                   ushort* __restrict__ xb) {
  int i = (blockIdx.x * 256 + threadIdx.x) * 4;
  float4 v = *reinterpret_cast<const float4*>(x + i);
  ushort4 o;
  o.x = f2bf(v.x); o.y = f2bf(v.y); o.z = f2bf(v.z); o.w = f2bf(v.w);
  *reinterpret_cast<ushort4*>(xb + i) = o;
}

// ------------------------------- prep: W[h][d][e] -> Wt[(m*12+h)*64+e][d] bf16 (B^T)
__global__ __launch_bounds__(256) void k_prep_w(const float* __restrict__ Wq,
                                                const float* __restrict__ Wk,
                                                const float* __restrict__ Wv,
                                                ushort* __restrict__ wt) {
  __shared__ ushort tile[64][65];
  const int mh = blockIdx.x;            // m*12 + h
  const int m = mh / 12, h = mh % 12;
  const int d0 = blockIdx.y * 64;
  const float* W = (m == 0 ? Wq : (m == 1 ? Wk : Wv)) + h * DIN * DH;
  ushort* outp = wt + (size_t)mh * DH * DIN;
  #pragma unroll
  for (int p = 0; p < 16; ++p) {
    int idx = p * 256 + threadIdx.x;
    int d = idx >> 6, e = idx & 63;
    tile[d][e] = f2bf(W[(d0 + d) * DH + e]);
  }
  __syncthreads();
  #pragma unroll
  for (int p = 0; p < 16; ++p) {
    int idx = p * 256 + threadIdx.x;
    int e = idx >> 6, d = idx & 63;
    outp[e * DIN + d0 + d] = tile[d][e];
  }
}

// ------------------------------------------------- QKV projection as ONE GEMM
// C[8192 x 2304] = xb[8192 x 768] * wt^T. 128x128 tile, BK=32, 4 waves (2x2) each 64x64.
// R6-proven 2-buf K-loop. NEW epilogue: per-wave LDS repack (XOR-swizzled both sides,
// V waves transposed) -> 8 coalesced global_store_dwordx4 per wave instead of 64
// scattered scalar stores (the old V^T scatter had 2KB lane stride = serial tail).
__global__ __launch_bounds__(256) void k_proj(const ushort* __restrict__ xb,
                                              const ushort* __restrict__ wt,
                                              ushort* __restrict__ qo,
                                              ushort* __restrict__ ko,
                                              ushort* __restrict__ vto) {
  __shared__ __align__(16) ushort Sb[16384];   // 32 KB: A bufs @0, B bufs @8192 (ushorts)

  const int brow = blockIdx.x * 128;
  const int bn   = blockIdx.y * 128;
  const int w    = threadIdx.x >> 6, lane = threadIdx.x & 63;
  const int lr   = lane & 15, lg = lane >> 4;
  const int wm   = w >> 1, wn = w & 1;

  const int srow  = threadIdx.x >> 2;
  const int sslot = (threadIdx.x & 3) ^ (srow & 3) ^ ((srow >> 2) & 3);
  const ushort* gA = xb + (size_t)(brow + srow) * DIN + sslot * 8;
  const ushort* gB = wt + (size_t)(bn   + srow) * DIN + sslot * 8;

  f32x4 acc[4][4];
  #pragma unroll
  for (int i = 0; i < 4; ++i)
    #pragma unroll
    for (int j = 0; j < 4; ++j) acc[i][j] = (f32x4){0.f, 0.f, 0.f, 0.f};

  const int fr   = (lr & 3) ^ ((lr >> 2) & 3);
  const int aoff = (lg ^ fr) * 8;

#define STAGEP(bi, tt) do {                                               \
    const int k0_ = (tt) * 32;                                            \
    ushort* la_ = Sb + (bi) * 4096 + threadIdx.x * 8;                     \
    ushort* lb_ = Sb + 8192 + (bi) * 4096 + threadIdx.x * 8;              \
    gload_lds16(gA + k0_,            la_);                                \
    gload_lds16(gA + k0_ + 64 * DIN, la_ + 2048);                         \
    gload_lds16(gB + k0_,            lb_);                                \
    gload_lds16(gB + k0_ + 64 * DIN, lb_ + 2048);                         \
  } while (0)

  STAGEP(0, 0);
  __syncthreads();

  int cur = 0;
  #pragma unroll 1
  for (int t = 0; t < 24; ++t) {
    if (t + 1 < 24) STAGEP(cur ^ 1, t + 1);
    short8 a[4], b[4];
    #pragma unroll
    for (int mi = 0; mi < 4; ++mi)
      a[mi] = *reinterpret_cast<const short8*>(&Sb[cur * 4096 + (wm * 64 + mi * 16 + lr) * 32 + aoff]);
    #pragma unroll
    for (int ci = 0; ci < 4; ++ci)
      b[ci] = *reinterpret_cast<const short8*>(&Sb[8192 + cur * 4096 + (wn * 64 + ci * 16 + lr) * 32 + aoff]);
    #pragma unroll
    for (int mi = 0; mi < 4; ++mi)
      #pragma unroll
      for (int ci = 0; ci < 4; ++ci)
        acc[mi][ci] = __builtin_amdgcn_mfma_f32_16x16x32_bf16(a[mi], b[ci], acc[mi][ci], 0, 0, 0);
    __syncthreads();
    cur ^= 1;
  }
#undef STAGEP

  // ---- epilogue: per-wave 8KB scratch repack -> coalesced 16B stores
  ushort* ldsw = Sb + w * 4096;                  // wave-private 64x64 tile
  const int colbase = bn + wn * 64;              // wave's global col base (64-aligned)
  const int mh = colbase >> 6;
  const int m = mh / 12, h = mh % 12;
  const int c = lane & 7;

  if (m < 2) {
    // layout [sl][e], e-chunk XOR-swizzled by row
    #pragma unroll
    for (int mi = 0; mi < 4; ++mi)
      #pragma unroll
      for (int ci = 0; ci < 4; ++ci)
        #pragma unroll
        for (int r = 0; r < 4; ++r) {
          int sl = mi * 16 + lg * 4 + r;
          int e  = ci * 16 + lr;
          ldsw[sl * 64 + (e ^ ((sl & 7) << 3))] = f2bf(acc[mi][ci][r]);
        }
    asm volatile("s_waitcnt lgkmcnt(0)" ::: "memory");
    ushort* dst = (m == 0) ? qo : ko;
    #pragma unroll
    for (int it = 0; it < 8; ++it) {
      int sl = it * 8 + (lane >> 3);
      short8 vv = *reinterpret_cast<const short8*>(&ldsw[sl * 64 + ((c * 8) ^ ((sl & 7) << 3))]);
      int rg = brow + wm * 64 + sl;
      int b_ = rg >> 10, s_ = rg & 1023;
      *reinterpret_cast<short8*>(dst + ((size_t)(b_ * 12 + h) * SQ + s_) * DH + c * 8) = vv;
    }
  } else {
    // V: transposed layout [e][sl], sl-chunk XOR-swizzled by e-row
    #pragma unroll
    for (int mi = 0; mi < 4; ++mi)
      #pragma unroll
      for (int ci = 0; ci < 4; ++ci)
        #pragma unroll
        for (int r = 0; r < 4; ++r) {
          int sl = mi * 16 + lg * 4 + r;
          int e  = ci * 16 + lr;
          ldsw[e * 64 + (sl ^ ((e & 7) << 3))] = f2bf(acc[mi][ci][r]);
        }
    asm volatile("s_waitcnt lgkmcnt(0)" ::: "memory");
    #pragma unroll
    for (int it = 0; it < 8; ++it) {
      int e = it * 8 + (lane >> 3);
      short8 vv = *reinterpret_cast<const short8*>(&ldsw[e * 64 + ((c * 8) ^ ((e & 7) << 3))]);
      int rg = brow + wm * 64 + c * 8;
      int b_ = rg >> 10, s_ = rg & 1023;
      *reinterpret_cast<short8*>(vto + ((size_t)(b_ * 12 + h) * DH + e) * SQ + s_) = vv;
    }
  }
}

// ------------------------------------------------- fused causal flash attention
// m214-style: swapped QK^T (S^T = mfma32(K, Q)), in-register softmax + in-register
// P->PV via pack + shfl_xor(32)+select. 4 waves x 32 q-rows; KVBLK=64; K/V^T in LDS
// (double-buffered, global_load_lds w=16, both-sides XOR swizzle). No P LDS.
__global__ __launch_bounds__(256, 3) void k_attn(const ushort* __restrict__ qi,
                                                 const ushort* __restrict__ ki,
                                                 const ushort* __restrict__ vti,
                                                 float* __restrict__ out) {
  __shared__ __align__(16) ushort Kb[2][64 * 64];
  __shared__ __align__(16) ushort Vb[2][64 * 64];

  const int f = blockIdx.x;
  const int g = f >> 8, r_ = f & 255;
  const int qt = ((r_ & 7) + g * 3) & 7;        // bijective, breaks 256-stride alignment
  const int bh = g * 32 + (r_ >> 3);
  const int b = bh / 12, h = bh % 12;
  const int w = threadIdx.x >> 6, lane = threadIdx.x & 63;
  const int ql = lane & 31, hi = lane >> 5;
  const int q0 = qt * 128 + w * 32;
  const int nt = (q0 >> 6) + 1;                 // this wave's kv-tile count
  const int ntmax = 2 * qt + 2;                 // block's kv-tile count
  const ushort* qb = qi  + (size_t)bh * SQ * DH;
  const ushort* kb = ki  + (size_t)bh * SQ * DH;
  const ushort* vb = vti + (size_t)bh * DH * SQ;

  short8 qf[4];
  #pragma unroll
  for (int m = 0; m < 4; ++m)
    qf[m] = *reinterpret_cast<const short8*>(qb + (size_t)(q0 + ql) * DH + m * 16 + hi * 8);

  f32x16 o0, o1;
  #pragma unroll
  for (int r = 0; r < 16; ++r) { o0[r] = 0.f; o1[r] = 0.f; }
  float m_run = -1e30f, l_run = 0.f;

#define STAGE(bufi, tt) do {                                                                   \
    const int kv0_ = (tt) * 64;                                                                \
    const int t0 = threadIdx.x, t1 = threadIdx.x + 256;                                        \
    gload_lds16(kb + (size_t)(kv0_ + (t0 >> 3)) * DH + (((t0 & 7) ^ ((t0 >> 3) & 7)) * 8),     \
                &Kb[bufi][0] + t0 * 8);                                                        \
    gload_lds16(kb + (size_t)(kv0_ + (t1 >> 3)) * DH + (((t1 & 7) ^ ((t1 >> 3) & 7)) * 8),     \
                &Kb[bufi][0] + t1 * 8);                                                        \
    gload_lds16(vb + (size_t)(t0 >> 3) * SQ + kv0_ + (((t0 & 7) ^ ((t0 >> 3) & 7)) * 8),       \
                &Vb[bufi][0] + t0 * 8);                                                        \
    gload_lds16(vb + (size_t)(t1 >> 3) * SQ + kv0_ + (((t1 & 7) ^ ((t1 >> 3) & 7)) * 8),       \
                &Vb[bufi][0] + t1 * 8);                                                        \
  } while (0)

  STAGE(0, 0);
  __syncthreads();

  int cur = 0;
  #pragma unroll 1
  for (int t = 0; t < ntmax; ++t) {
    if (t + 1 < ntmax) STAGE(cur ^ 1, t + 1);

    if (t < nt) {
      const int kv0 = t * 64;
      const ushort* Kc = &Kb[cur][0];
      const ushort* Vc = &Vb[cur][0];

      f32x16 s0, s1;
      #pragma unroll
      for (int r = 0; r < 16; ++r) { s0[r] = 0.f; s1[r] = 0.f; }
      #pragma unroll
      for (int m = 0; m < 4; ++m) {
        short8 kf = *reinterpret_cast<const short8*>(Kc + ql * 64 + ((2 * m + hi) ^ (ql & 7)) * 8);
        s0 = __builtin_amdgcn_mfma_f32_32x32x16_bf16(kf, qf[m], s0, 0, 0, 0);
      }
      #pragma unroll
      for (int m = 0; m < 4; ++m) {
        short8 kf = *reinterpret_cast<const short8*>(Kc + (32 + ql) * 64 + ((2 * m + hi) ^ (ql & 7)) * 8);
        s1 = __builtin_amdgcn_mfma_f32_32x32x16_bf16(kf, qf[m], s1, 0, 0, 0);
      }

      if (t == nt - 1) {
        const int qg = q0 + ql;
        #pragma unroll
        for (int r = 0; r < 16; ++r) {
          int kvl = (r & 3) + 8 * (r >> 2) + 4 * hi;
          if (kv0 + kvl      > qg) s0[r] = -1e30f;
          if (kv0 + 32 + kvl > qg) s1[r] = -1e30f;
        }
      }

      float mt = s0[0];
      #pragma unroll
      for (int r = 1; r < 16; ++r) mt = fmaxf(mt, s0[r]);
      #pragma unroll
      for (int r = 0; r < 16; ++r) mt = fmaxf(mt, s1[r]);
      mt = fmaxf(mt, __shfl_xor(mt, 32));
      if (__any(mt > m_run + 40.0f)) {
        float mnew = fmaxf(m_run, mt);
        float corr = exp2f((m_run - mnew) * SCL2);
        l_run *= corr; m_run = mnew;
        #pragma unroll
        for (int r = 0; r < 16; ++r) {
          float cr = __shfl(corr, (r & 3) + 8 * (r >> 2) + 4 * hi);
          o0[r] *= cr; o1[r] *= cr;
        }
      }
      float ts = 0.f;
      #pragma unroll
      for (int r = 0; r < 16; ++r) {
        s0[r] = exp2f((s0[r] - m_run) * SCL2); ts += s0[r];
        s1[r] = exp2f((s1[r] - m_run) * SCL2); ts += s1[r];
      }
      ts += __shfl_xor(ts, 32);
      l_run += ts;

#define PV_CHUNK(SV, CC, KC) do {                                                              \
        unsigned wa = pk2(SV[(CC) * 8 + 0], SV[(CC) * 8 + 1]);                                 \
        unsigned wb = pk2(SV[(CC) * 8 + 2], SV[(CC) * 8 + 3]);                                 \
        unsigned wc = pk2(SV[(CC) * 8 + 4], SV[(CC) * 8 + 5]);                                 \
        unsigned wd = pk2(SV[(CC) * 8 + 6], SV[(CC) * 8 + 7]);                                 \
        unsigned xa = __shfl_xor(wa, 32), xb2 = __shfl_xor(wb, 32);                            \
        unsigned xc = __shfl_xor(wc, 32), xd = __shfl_xor(wd, 32);                             \
        uint4 pw;                                                                              \
        pw.x = hi ? xc : wa;  pw.y = hi ? xd : wb;                                             \
        pw.z = hi ? wc : xa;  pw.w = hi ? wd : xb2;                                            \
        short8 pa = *reinterpret_cast<short8*>(&pw);                                           \
        short8 vf0 = *reinterpret_cast<const short8*>(Vc + ql * 64 +                           \
                       ((2 * (KC) + hi) ^ (ql & 7)) * 8);                                      \
        o0 = __builtin_amdgcn_mfma_f32_32x32x16_bf16(pa, vf0, o0, 0, 0, 0);                    \
        short8 vf1 = *reinterpret_cast<const short8*>(Vc + (32 + ql) * 64 +                    \
                       ((2 * (KC) + hi) ^ (ql & 7)) * 8);                                      \
        o1 = __builtin_amdgcn_mfma_f32_32x32x16_bf16(pa, vf1, o1, 0, 0, 0);                    \
      } while (0)

      PV_CHUNK(s0, 0, 0);
      PV_CHUNK(s0, 1, 1);
      PV_CHUNK(s1, 0, 2);
      PV_CHUNK(s1, 1, 3);
#undef PV_CHUNK
    }

    __syncthreads();
    cur ^= 1;
  }
#undef STAGE

  float rl = 1.0f / l_run;
  #pragma unroll
  for (int r = 0; r < 16; ++r) {
    int base = (r & 3) + 8 * (r >> 2) + 4 * hi;
    float sc_ = __shfl(rl, base);
    int qg = q0 + base;
    float* op = out + ((size_t)b * SQ + qg) * (NH * DH) + h * DH;
    op[ql]      = o0[r] * sc_;
    op[32 + ql] = o1[r] * sc_;
  }
}

extern "C" void kernel_launch(void* const* d_in, const int* in_sizes, int n_in,
                              void* d_out, int out_size, void* d_ws, size_t ws_size,
                              hipStream_t stream) {
  const float* x  = (const float*)d_in[0];
  const float* Wq = (const float*)d_in[1];
  const float* Wk = (const float*)d_in[2];
  const float* Wv = (const float*)d_in[3];
  float* out = (float*)d_out;

  char* ws = (char*)d_ws;
  ushort* xb = (ushort*)(ws);
  ushort* wt = (ushort*)(ws + 12582912);
  ushort* q  = (ushort*)(ws + 16121856);
  ushort* k  = (ushort*)(ws + 28704768);
  ushort* vt = (ushort*)(ws + 41287680);

  k_convert_x<<<6144, 256, 0, stream>>>(x, xb);
  k_prep_w<<<dim3(36, 12), 256, 0, stream>>>(Wq, Wk, Wv, wt);
  k_proj<<<dim3(64, 18), 256, 0, stream>>>(xb, wt, q, k, vt);
  k_attn<<<768, 256, 0, stream>>>(q, k, vt, out);
}

// Round 9
// 171.314 us; speedup vs baseline: 1.1660x; 1.0370x over previous
//
#include <hip/hip_runtime.h>

typedef short short8 __attribute__((ext_vector_type(8)));
typedef float f32x4 __attribute__((ext_vector_type(4)));
typedef float f32x16 __attribute__((ext_vector_type(16)));

#define SQ   1024
#define DIN  768
#define NH   12
#define DH   64
#define SCL2 0.1803368801111243f   /* 0.125 * log2(e) */

static __device__ __forceinline__ ushort f2bf(float f) {
  union { float f; unsigned u; } v; v.f = f;
  unsigned u = v.u;
  unsigned r = (u + 0x7FFFu + ((u >> 16) & 1u)) >> 16;
  return (ushort)r;
}
// hardware packed f32->bf16 (RNE); dst.lo=a, dst.hi=b
static __device__ __forceinline__ unsigned cvtpk(float a, float b) {
  unsigned r;
  asm("v_cvt_pk_bf16_f32 %0, %1, %2" : "=v"(r) : "v"(a), "v"(b));
  return r;
}

static __device__ __forceinline__ void gload_lds16(const ushort* g, ushort* l) {
  __builtin_amdgcn_global_load_lds(
      (const __attribute__((address_space(1))) unsigned*)(g),
      (__attribute__((address_space(3))) unsigned*)(l),
      16, 0, 0);
}

// ---------------------------------------------------------------- prep: x -> bf16
__global__ __launch_bounds__(256) void k_convert_x(const float* __restrict__ x,
                                                   ushort* __restrict__ xb) {
  int i = (blockIdx.x * 256 + threadIdx.x) * 8;
  float4 v0 = *reinterpret_cast<const float4*>(x + i);
  float4 v1 = *reinterpret_cast<const float4*>(x + i + 4);
  uint4 o;
  o.x = cvtpk(v0.x, v0.y); o.y = cvtpk(v0.z, v0.w);
  o.z = cvtpk(v1.x, v1.y); o.w = cvtpk(v1.z, v1.w);
  *reinterpret_cast<uint4*>(xb + i) = o;
}

// ------------------------------- prep: W[h][d][e] -> Wt[(m*12+h)*64+e][d] bf16 (B^T)
__global__ __launch_bounds__(256) void k_prep_w(const float* __restrict__ Wq,
                                                const float* __restrict__ Wk,
                                                const float* __restrict__ Wv,
                                                ushort* __restrict__ wt) {
  __shared__ ushort tile[64][65];
  const int mh = blockIdx.x;            // m*12 + h
  const int m = mh / 12, h = mh % 12;
  const int d0 = blockIdx.y * 64;
  const float* W = (m == 0 ? Wq : (m == 1 ? Wk : Wv)) + h * DIN * DH;
  ushort* outp = wt + (size_t)mh * DH * DIN;
  #pragma unroll
  for (int p = 0; p < 16; ++p) {
    int idx = p * 256 + threadIdx.x;
    int d = idx >> 6, e = idx & 63;
    tile[d][e] = f2bf(W[(d0 + d) * DH + e]);
  }
  __syncthreads();
  #pragma unroll
  for (int p = 0; p < 16; ++p) {
    int idx = p * 256 + threadIdx.x;
    int e = idx >> 6, d = idx & 63;
    outp[e * DIN + d0 + d] = tile[d][e];
  }
}

// ------------------------------------------------- QKV projection as ONE GEMM
// C[8192 x 2304] = xb[8192 x 768] * wt^T. Tile 256x128, BK=32, 4 waves (2x2),
// per-wave 128x64 (raises compute/LDS-byte 1.33x over 64x64 -> MFMA-bound).
// 2-buf gload_lds K-loop (R6-proven) + repack epilogue (R8-proven, 2 passes).
__global__ __launch_bounds__(256, 2) void k_proj(const ushort* __restrict__ xb,
                                                 const ushort* __restrict__ wt,
                                                 ushort* __restrict__ qo,
                                                 ushort* __restrict__ ko,
                                                 ushort* __restrict__ vto) {
  __shared__ __align__(16) ushort Sb[24576];   // 48 KB: A 2buf @0 (2x8192), B 2buf @16384 (2x4096)

  const int brow = blockIdx.x * 256;
  const int bn   = blockIdx.y * 128;
  const int w    = threadIdx.x >> 6, lane = threadIdx.x & 63;
  const int lr   = lane & 15, lg = lane >> 4;
  const int wm   = w >> 1, wn = w & 1;

  const int srow  = threadIdx.x >> 2;                          // 0..63
  const int sslot = (threadIdx.x & 3) ^ (srow & 3) ^ ((srow >> 2) & 3);
  const ushort* gA = xb + (size_t)(brow + srow) * DIN + sslot * 8;
  const ushort* gB = wt + (size_t)(bn   + srow) * DIN + sslot * 8;

  f32x4 acc[8][4];
  #pragma unroll
  for (int i = 0; i < 8; ++i)
    #pragma unroll
    for (int j = 0; j < 4; ++j) acc[i][j] = (f32x4){0.f, 0.f, 0.f, 0.f};

  const int fr   = (lr & 3) ^ ((lr >> 2) & 3);
  const int aoff = (lg ^ fr) * 8;

#define STAGEP(bi, tt) do {                                               \
    const int k0_ = (tt) * 32;                                            \
    ushort* la_ = Sb + (bi) * 8192 + threadIdx.x * 8;                     \
    ushort* lb_ = Sb + 16384 + (bi) * 4096 + threadIdx.x * 8;             \
    gload_lds16(gA + k0_,             la_);                               \
    gload_lds16(gA + k0_ +  64 * DIN, la_ + 2048);                        \
    gload_lds16(gA + k0_ + 128 * DIN, la_ + 4096);                        \
    gload_lds16(gA + k0_ + 192 * DIN, la_ + 6144);                        \
    gload_lds16(gB + k0_,             lb_);                               \
    gload_lds16(gB + k0_ +  64 * DIN, lb_ + 2048);                        \
  } while (0)

  STAGEP(0, 0);
  __syncthreads();

  int cur = 0;
  #pragma unroll 1
  for (int t = 0; t < 24; ++t) {
    if (t + 1 < 24) STAGEP(cur ^ 1, t + 1);
    short8 a[8], b[4];
    #pragma unroll
    for (int mi = 0; mi < 8; ++mi)
      a[mi] = *reinterpret_cast<const short8*>(&Sb[cur * 8192 + (wm * 128 + mi * 16 + lr) * 32 + aoff]);
    #pragma unroll
    for (int ci = 0; ci < 4; ++ci)
      b[ci] = *reinterpret_cast<const short8*>(&Sb[16384 + cur * 4096 + (wn * 64 + ci * 16 + lr) * 32 + aoff]);
    #pragma unroll
    for (int mi = 0; mi < 8; ++mi)
      #pragma unroll
      for (int ci = 0; ci < 4; ++ci)
        acc[mi][ci] = __builtin_amdgcn_mfma_f32_16x16x32_bf16(a[mi], b[ci], acc[mi][ci], 0, 0, 0);
    __syncthreads();
    cur ^= 1;
  }
#undef STAGEP

  // ---- epilogue: per-wave 8KB scratch repack (2 row-passes) -> coalesced 16B stores
  ushort* ldsw = Sb + w * 4096;                  // wave-private 64x64 ushort tile
  const int mh = blockIdx.y * 2 + wn;
  const int m = mh / 12, h = mh % 12;
  const int c = lane & 7;

  #pragma unroll
  for (int p = 0; p < 2; ++p) {
    if (m < 2) {
      // layout [sl][e], e-chunk XOR-swizzled by row
      #pragma unroll
      for (int mi2 = 0; mi2 < 4; ++mi2)
        #pragma unroll
        for (int ci = 0; ci < 4; ++ci)
          #pragma unroll
          for (int r = 0; r < 4; ++r) {
            int sl = mi2 * 16 + lg * 4 + r;
            int e  = ci * 16 + lr;
            ldsw[sl * 64 + (e ^ ((sl & 7) << 3))] = f2bf(acc[p * 4 + mi2][ci][r]);
          }
      asm volatile("s_waitcnt lgkmcnt(0)" ::: "memory");
      ushort* dst = (m == 0) ? qo : ko;
      #pragma unroll
      for (int it = 0; it < 8; ++it) {
        int sl = it * 8 + (lane >> 3);
        short8 vv = *reinterpret_cast<const short8*>(&ldsw[sl * 64 + ((c * 8) ^ ((sl & 7) << 3))]);
        int rg = brow + wm * 128 + p * 64 + sl;
        int b_ = rg >> 10, s_ = rg & 1023;
        *reinterpret_cast<short8*>(dst + ((size_t)(b_ * 12 + h) * SQ + s_) * DH + c * 8) = vv;
      }
    } else {
      // V: transposed layout [e][sl], sl-chunk XOR-swizzled by e-row
      #pragma unroll
      for (int mi2 = 0; mi2 < 4; ++mi2)
        #pragma unroll
        for (int ci = 0; ci < 4; ++ci)
          #pragma unroll
          for (int r = 0; r < 4; ++r) {
            int sl = mi2 * 16 + lg * 4 + r;
            int e  = ci * 16 + lr;
            ldsw[e * 64 + (sl ^ ((e & 7) << 3))] = f2bf(acc[p * 4 + mi2][ci][r]);
          }
      asm volatile("s_waitcnt lgkmcnt(0)" ::: "memory");
      #pragma unroll
      for (int it = 0; it < 8; ++it) {
        int e = it * 8 + (lane >> 3);
        short8 vv = *reinterpret_cast<const short8*>(&ldsw[e * 64 + ((c * 8) ^ ((e & 7) << 3))]);
        int rg = brow + wm * 128 + p * 64 + c * 8;
        int b_ = rg >> 10, s_ = rg & 1023;
        *reinterpret_cast<short8*>(vto + ((size_t)(b_ * 12 + h) * DH + e) * SQ + s_) = vv;
      }
    }
    // per-wave scratch reuse across passes is safe: DS ops are in-order per wave
  }
}

// ------------------------------------------------- fused causal flash attention
// swapped QK^T (S^T = mfma32(K, Q)), in-register softmax + in-register P->PV
// (cvt_pk_bf16 + shfl_xor(32)+select). 4 waves x 32 q-rows; KVBLK=64; K/V^T in LDS
// (double-buffered, global_load_lds w=16, both-sides XOR swizzle). No P LDS.
__global__ __launch_bounds__(256, 3) void k_attn(const ushort* __restrict__ qi,
                                                 const ushort* __restrict__ ki,
                                                 const ushort* __restrict__ vti,
                                                 float* __restrict__ out) {
  __shared__ __align__(16) ushort Kb[2][64 * 64];
  __shared__ __align__(16) ushort Vb[2][64 * 64];

  const int f = blockIdx.x;
  const int g = f >> 8, r_ = f & 255;
  const int qt = ((r_ & 7) + g * 3) & 7;        // bijective, breaks 256-stride alignment
  const int bh = g * 32 + (r_ >> 3);
  const int b = bh / 12, h = bh % 12;
  const int w = threadIdx.x >> 6, lane = threadIdx.x & 63;
  const int ql = lane & 31, hi = lane >> 5;
  const int q0 = qt * 128 + w * 32;
  const int nt = (q0 >> 6) + 1;                 // this wave's kv-tile count
  const int ntmax = 2 * qt + 2;                 // block's kv-tile count
  const ushort* qb = qi  + (size_t)bh * SQ * DH;
  const ushort* kb = ki  + (size_t)bh * SQ * DH;
  const ushort* vb = vti + (size_t)bh * DH * SQ;

  short8 qf[4];
  #pragma unroll
  for (int m = 0; m < 4; ++m)
    qf[m] = *reinterpret_cast<const short8*>(qb + (size_t)(q0 + ql) * DH + m * 16 + hi * 8);

  f32x16 o0, o1;
  #pragma unroll
  for (int r = 0; r < 16; ++r) { o0[r] = 0.f; o1[r] = 0.f; }
  float m_run = -1e30f, l_run = 0.f;

#define STAGE(bufi, tt) do {                                                                   \
    const int kv0_ = (tt) * 64;                                                                \
    const int t0 = threadIdx.x, t1 = threadIdx.x + 256;                                        \
    gload_lds16(kb + (size_t)(kv0_ + (t0 >> 3)) * DH + (((t0 & 7) ^ ((t0 >> 3) & 7)) * 8),     \
                &Kb[bufi][0] + t0 * 8);                                                        \
    gload_lds16(kb + (size_t)(kv0_ + (t1 >> 3)) * DH + (((t1 & 7) ^ ((t1 >> 3) & 7)) * 8),     \
                &Kb[bufi][0] + t1 * 8);                                                        \
    gload_lds16(vb + (size_t)(t0 >> 3) * SQ + kv0_ + (((t0 & 7) ^ ((t0 >> 3) & 7)) * 8),       \
                &Vb[bufi][0] + t0 * 8);                                                        \
    gload_lds16(vb + (size_t)(t1 >> 3) * SQ + kv0_ + (((t1 & 7) ^ ((t1 >> 3) & 7)) * 8),       \
                &Vb[bufi][0] + t1 * 8);                                                        \
  } while (0)

  STAGE(0, 0);
  __syncthreads();

  int cur = 0;
  #pragma unroll 1
  for (int t = 0; t < ntmax; ++t) {
    if (t + 1 < ntmax) STAGE(cur ^ 1, t + 1);

    if (t < nt) {
      const int kv0 = t * 64;
      const ushort* Kc = &Kb[cur][0];
      const ushort* Vc = &Vb[cur][0];

      f32x16 s0, s1;
      #pragma unroll
      for (int r = 0; r < 16; ++r) { s0[r] = 0.f; s1[r] = 0.f; }
      #pragma unroll
      for (int m = 0; m < 4; ++m) {
        short8 kf = *reinterpret_cast<const short8*>(Kc + ql * 64 + ((2 * m + hi) ^ (ql & 7)) * 8);
        s0 = __builtin_amdgcn_mfma_f32_32x32x16_bf16(kf, qf[m], s0, 0, 0, 0);
      }
      #pragma unroll
      for (int m = 0; m < 4; ++m) {
        short8 kf = *reinterpret_cast<const short8*>(Kc + (32 + ql) * 64 + ((2 * m + hi) ^ (ql & 7)) * 8);
        s1 = __builtin_amdgcn_mfma_f32_32x32x16_bf16(kf, qf[m], s1, 0, 0, 0);
      }

      if (t == nt - 1) {
        const int qg = q0 + ql;
        #pragma unroll
        for (int r = 0; r < 16; ++r) {
          int kvl = (r & 3) + 8 * (r >> 2) + 4 * hi;
          if (kv0 + kvl      > qg) s0[r] = -1e30f;
          if (kv0 + 32 + kvl > qg) s1[r] = -1e30f;
        }
      }

      float mt = s0[0];
      #pragma unroll
      for (int r = 1; r < 16; ++r) mt = fmaxf(mt, s0[r]);
      #pragma unroll
      for (int r = 0; r < 16; ++r) mt = fmaxf(mt, s1[r]);
      mt = fmaxf(mt, __shfl_xor(mt, 32));
      if (__any(mt > m_run + 40.0f)) {
        float mnew = fmaxf(m_run, mt);
        float corr = exp2f((m_run - mnew) * SCL2);
        l_run *= corr; m_run = mnew;
        #pragma unroll
        for (int r = 0; r < 16; ++r) {
          float cr = __shfl(corr, (r & 3) + 8 * (r >> 2) + 4 * hi);
          o0[r] *= cr; o1[r] *= cr;
        }
      }
      float ts = 0.f;
      #pragma unroll
      for (int r = 0; r < 16; ++r) {
        s0[r] = exp2f((s0[r] - m_run) * SCL2); ts += s0[r];
        s1[r] = exp2f((s1[r] - m_run) * SCL2); ts += s1[r];
      }
      ts += __shfl_xor(ts, 32);
      l_run += ts;

#define PV_CHUNK(SV, CC, KC) do {                                                              \
        unsigned wa = cvtpk(SV[(CC) * 8 + 0], SV[(CC) * 8 + 1]);                               \
        unsigned wb = cvtpk(SV[(CC) * 8 + 2], SV[(CC) * 8 + 3]);                               \
        unsigned wc = cvtpk(SV[(CC) * 8 + 4], SV[(CC) * 8 + 5]);                               \
        unsigned wd = cvtpk(SV[(CC) * 8 + 6], SV[(CC) * 8 + 7]);                               \
        unsigned xa = __shfl_xor(wa, 32), xb2 = __shfl_xor(wb, 32);                            \
        unsigned xc = __shfl_xor(wc, 32), xd = __shfl_xor(wd, 32);                             \
        uint4 pw;                                                                              \
        pw.x = hi ? xc : wa;  pw.y = hi ? xd : wb;                                             \
        pw.z = hi ? wc : xa;  pw.w = hi ? wd : xb2;                                            \
        short8 pa = *reinterpret_cast<short8*>(&pw);                                           \
        short8 vf0 = *reinterpret_cast<const short8*>(Vc + ql * 64 +                           \
                       ((2 * (KC) + hi) ^ (ql & 7)) * 8);                                      \
        o0 = __builtin_amdgcn_mfma_f32_32x32x16_bf16(pa, vf0, o0, 0, 0, 0);                    \
        short8 vf1 = *reinterpret_cast<const short8*>(Vc + (32 + ql) * 64 +                    \
                       ((2 * (KC) + hi) ^ (ql & 7)) * 8);                                      \
        o1 = __builtin_amdgcn_mfma_f32_32x32x16_bf16(pa, vf1, o1, 0, 0, 0);                    \
      } while (0)

      PV_CHUNK(s0, 0, 0);
      PV_CHUNK(s0, 1, 1);
      PV_CHUNK(s1, 0, 2);
      PV_CHUNK(s1, 1, 3);
#undef PV_CHUNK
    }

    __syncthreads();
    cur ^= 1;
  }
#undef STAGE

  float rl = 1.0f / l_run;
  #pragma unroll
  for (int r = 0; r < 16; ++r) {
    int base = (r & 3) + 8 * (r >> 2) + 4 * hi;
    float sc_ = __shfl(rl, base);
    int qg = q0 + base;
    float* op = out + ((size_t)b * SQ + qg) * (NH * DH) + h * DH;
    op[ql]      = o0[r] * sc_;
    op[32 + ql] = o1[r] * sc_;
  }
}

extern "C" void kernel_launch(void* const* d_in, const int* in_sizes, int n_in,
                              void* d_out, int out_size, void* d_ws, size_t ws_size,
                              hipStream_t stream) {
  const float* x  = (const float*)d_in[0];
  const float* Wq = (const float*)d_in[1];
  const float* Wk = (const float*)d_in[2];
  const float* Wv = (const float*)d_in[3];
  float* out = (float*)d_out;

  char* ws = (char*)d_ws;
  ushort* xb = (ushort*)(ws);
  ushort* wt = (ushort*)(ws + 12582912);
  ushort* q  = (ushort*)(ws + 16121856);
  ushort* k  = (ushort*)(ws + 28704768);
  ushort* vt = (ushort*)(ws + 41287680);

  k_convert_x<<<3072, 256, 0, stream>>>(x, xb);
  k_prep_w<<<dim3(36, 12), 256, 0, stream>>>(Wq, Wk, Wv, wt);
  k_proj<<<dim3(32, 18), 256, 0, stream>>>(xb, wt, q, k, vt);
  k_attn<<<768, 256, 0, stream>>>(q, k, vt, out);
}

// Round 10
// 169.660 us; speedup vs baseline: 1.1774x; 1.0098x over previous
//
#include <hip/hip_runtime.h>

typedef short short8 __attribute__((ext_vector_type(8)));
typedef float f32x4 __attribute__((ext_vector_type(4)));
typedef float f32x16 __attribute__((ext_vector_type(16)));

#define SQ   1024
#define DIN  768
#define NH   12
#define DH   64
#define SCL2 0.1803368801111243f   /* 0.125 * log2(e) */

static __device__ __forceinline__ ushort f2bf(float f) {
  union { float f; unsigned u; } v; v.f = f;
  unsigned u = v.u;
  unsigned r = (u + 0x7FFFu + ((u >> 16) & 1u)) >> 16;
  return (ushort)r;
}
// hardware packed f32->bf16 (RNE); dst.lo=a, dst.hi=b
static __device__ __forceinline__ unsigned cvtpk(float a, float b) {
  unsigned r;
  asm("v_cvt_pk_bf16_f32 %0, %1, %2" : "=v"(r) : "v"(a), "v"(b));
  return r;
}

static __device__ __forceinline__ void gload_lds16(const ushort* g, ushort* l) {
  __builtin_amdgcn_global_load_lds(
      (const __attribute__((address_space(1))) unsigned*)(g),
      (__attribute__((address_space(3))) unsigned*)(l),
      16, 0, 0);
}

// ---------------------------------------------------------------- prep: x -> bf16
__global__ __launch_bounds__(256) void k_convert_x(const float* __restrict__ x,
                                                   ushort* __restrict__ xb) {
  int i = (blockIdx.x * 256 + threadIdx.x) * 8;
  float4 v0 = *reinterpret_cast<const float4*>(x + i);
  float4 v1 = *reinterpret_cast<const float4*>(x + i + 4);
  uint4 o;
  o.x = cvtpk(v0.x, v0.y); o.y = cvtpk(v0.z, v0.w);
  o.z = cvtpk(v1.x, v1.y); o.w = cvtpk(v1.z, v1.w);
  *reinterpret_cast<uint4*>(xb + i) = o;
}

// ------------------------------- prep: W[h][d][e] -> Wt[(m*12+h)*64+e][d] bf16 (B^T)
__global__ __launch_bounds__(256) void k_prep_w(const float* __restrict__ Wq,
                                                const float* __restrict__ Wk,
                                                const float* __restrict__ Wv,
                                                ushort* __restrict__ wt) {
  __shared__ ushort tile[64][65];
  const int mh = blockIdx.x;            // m*12 + h
  const int m = mh / 12, h = mh % 12;
  const int d0 = blockIdx.y * 64;
  const float* W = (m == 0 ? Wq : (m == 1 ? Wk : Wv)) + h * DIN * DH;
  ushort* outp = wt + (size_t)mh * DH * DIN;
  #pragma unroll
  for (int p = 0; p < 16; ++p) {
    int idx = p * 256 + threadIdx.x;
    int d = idx >> 6, e = idx & 63;
    tile[d][e] = f2bf(W[(d0 + d) * DH + e]);
  }
  __syncthreads();
  #pragma unroll
  for (int p = 0; p < 16; ++p) {
    int idx = p * 256 + threadIdx.x;
    int e = idx >> 6, d = idx & 63;
    outp[e * DIN + d0 + d] = tile[d][e];
  }
}

// ------------------------------------------------- QKV projection as ONE GEMM
// C[8192 x 2304] = xb[8192 x 768] * wt^T. 128x128 tile, BK=32, 4 waves (2x2) each
// 64x64 via mfma_32x32x16. T3+T4: 3 LDS buffers, depth-2 prefetch, counted
// s_waitcnt vmcnt(4) + raw s_barrier (no vmcnt(0) drain in steady state).
// R8-proven repack epilogue (adapted to 32x32 C layout).
__global__ __launch_bounds__(256) void k_proj(const ushort* __restrict__ xb,
                                              const ushort* __restrict__ wt,
                                              ushort* __restrict__ qo,
                                              ushort* __restrict__ ko,
                                              ushort* __restrict__ vto) {
  __shared__ __align__(16) ushort Sb[24576];   // 48 KB: A 3x8KB @0, B 3x8KB @12288

  const int brow = blockIdx.x * 128;
  const int bn   = blockIdx.y * 128;
  const int w    = threadIdx.x >> 6, lane = threadIdx.x & 63;
  const int ql   = lane & 31, hi = lane >> 5;
  const int wm   = w >> 1, wn = w & 1;

  // staging: 64B LDS rows (32 K-ushorts), 4 chunk-slots of 16B; involution swizzle
  const int srow  = threadIdx.x >> 2;                          // 0..63
  const int sslot = (threadIdx.x & 3) ^ (srow & 3) ^ ((srow >> 2) & 3);
  const ushort* gA = xb + (size_t)(brow + srow) * DIN + sslot * 8;
  const ushort* gB = wt + (size_t)(bn   + srow) * DIN + sslot * 8;

  f32x16 acc[2][2];
  #pragma unroll
  for (int i = 0; i < 2; ++i)
    #pragma unroll
    for (int j = 0; j < 2; ++j)
      #pragma unroll
      for (int r = 0; r < 16; ++r) acc[i][j][r] = 0.f;

  const int frq = (ql & 3) ^ ((ql >> 2) & 3);     // f(row) depends on ql only

#define STAGEP(bi, tt) do {                                               \
    const int k0_ = (tt) * 32;                                            \
    ushort* la_ = Sb + (bi) * 4096 + threadIdx.x * 8;                     \
    ushort* lb_ = Sb + 12288 + (bi) * 4096 + threadIdx.x * 8;             \
    gload_lds16(gA + k0_,            la_);                                \
    gload_lds16(gA + k0_ + 64 * DIN, la_ + 2048);                         \
    gload_lds16(gB + k0_,            lb_);                                \
    gload_lds16(gB + k0_ + 64 * DIN, lb_ + 2048);                         \
  } while (0)

  STAGEP(0, 0);
  STAGEP(1, 1);

  int cur = 0;
  #pragma unroll 1
  for (int t = 0; t < 24; ++t) {
    // own loads for tile t done (oldest 4); keep tiles t+1 (and t+2) in flight
    if (t < 23) asm volatile("s_waitcnt vmcnt(4)" ::: "memory");
    else        asm volatile("s_waitcnt vmcnt(0)" ::: "memory");
    __builtin_amdgcn_sched_barrier(0);
    __builtin_amdgcn_s_barrier();           // now ALL waves' tile-t loads complete
    __builtin_amdgcn_sched_barrier(0);
    if (t + 2 < 24) {
      int nb = cur + 2; if (nb >= 3) nb -= 3;
      STAGEP(nb, t + 2);                    // writes buf last read at iter t-1
    }
    short8 a[2][2], b[2][2];
    #pragma unroll
    for (int ai = 0; ai < 2; ++ai) {
      const int row = wm * 64 + ai * 32 + ql;
      #pragma unroll
      for (int ks = 0; ks < 2; ++ks)
        a[ai][ks] = *reinterpret_cast<const short8*>(
            &Sb[cur * 4096 + row * 32 + (((ks * 2 + hi) ^ frq) * 8)]);
    }
    #pragma unroll
    for (int ci = 0; ci < 2; ++ci) {
      const int row = wn * 64 + ci * 32 + ql;
      #pragma unroll
      for (int ks = 0; ks < 2; ++ks)
        b[ci][ks] = *reinterpret_cast<const short8*>(
            &Sb[12288 + cur * 4096 + row * 32 + (((ks * 2 + hi) ^ frq) * 8)]);
    }
    #pragma unroll
    for (int ai = 0; ai < 2; ++ai)
      #pragma unroll
      for (int ci = 0; ci < 2; ++ci) {
        acc[ai][ci] = __builtin_amdgcn_mfma_f32_32x32x16_bf16(a[ai][0], b[ci][0], acc[ai][ci], 0, 0, 0);
        acc[ai][ci] = __builtin_amdgcn_mfma_f32_32x32x16_bf16(a[ai][1], b[ci][1], acc[ai][ci], 0, 0, 0);
      }
    cur += 1; if (cur >= 3) cur = 0;
  }
#undef STAGEP

  __syncthreads();   // scratch below overlaps live buffers of the last iteration

  // ---- epilogue: per-wave 8KB scratch repack -> coalesced 16B stores
  // C layout (32x32): col = ql, row = (r&3)+8*(r>>2)+4*hi
  ushort* ldsw = Sb + w * 4096;                  // wave-private 64x64 ushort tile
  const int mh = blockIdx.y * 2 + wn;
  const int m = mh / 12, h = mh % 12;
  const int c = lane & 7;

  if (m < 2) {
    // layout [sl][e], e-chunk XOR-swizzled by row
    #pragma unroll
    for (int ai = 0; ai < 2; ++ai)
      #pragma unroll
      for (int ci = 0; ci < 2; ++ci)
        #pragma unroll
        for (int r = 0; r < 16; ++r) {
          int sl = ai * 32 + (r & 3) + 8 * (r >> 2) + 4 * hi;
          int e  = ci * 32 + ql;
          ldsw[sl * 64 + (e ^ ((sl & 7) << 3))] = f2bf(acc[ai][ci][r]);
        }
    asm volatile("s_waitcnt lgkmcnt(0)" ::: "memory");
    ushort* dst = (m == 0) ? qo : ko;
    #pragma unroll
    for (int it = 0; it < 8; ++it) {
      int sl = it * 8 + (lane >> 3);
      short8 vv = *reinterpret_cast<const short8*>(&ldsw[sl * 64 + ((c * 8) ^ ((sl & 7) << 3))]);
      int rg = brow + wm * 64 + sl;
      int b_ = rg >> 10, s_ = rg & 1023;
      *reinterpret_cast<short8*>(dst + ((size_t)(b_ * 12 + h) * SQ + s_) * DH + c * 8) = vv;
    }
  } else {
    // V: transposed layout [e][sl], sl-chunk XOR-swizzled by e-row
    #pragma unroll
    for (int ai = 0; ai < 2; ++ai)
      #pragma unroll
      for (int ci = 0; ci < 2; ++ci)
        #pragma unroll
        for (int r = 0; r < 16; ++r) {
          int sl = ai * 32 + (r & 3) + 8 * (r >> 2) + 4 * hi;
          int e  = ci * 32 + ql;
          ldsw[e * 64 + (sl ^ ((e & 7) << 3))] = f2bf(acc[ai][ci][r]);
        }
    asm volatile("s_waitcnt lgkmcnt(0)" ::: "memory");
    #pragma unroll
    for (int it = 0; it < 8; ++it) {
      int e = it * 8 + (lane >> 3);
      short8 vv = *reinterpret_cast<const short8*>(&ldsw[e * 64 + ((c * 8) ^ ((e & 7) << 3))]);
      int rg = brow + wm * 64 + c * 8;
      int b_ = rg >> 10, s_ = rg & 1023;
      *reinterpret_cast<short8*>(vto + ((size_t)(b_ * 12 + h) * DH + e) * SQ + s_) = vv;
    }
  }
}

// ------------------------------------------------- fused causal flash attention
// swapped QK^T (S^T = mfma32(K, Q)), in-register softmax + in-register P->PV
// (cvt_pk_bf16 + shfl_xor(32)+select). 4 waves x 32 q-rows; KVBLK=64; K/V^T in LDS
// (double-buffered, global_load_lds w=16, both-sides XOR swizzle). No P LDS.
__global__ __launch_bounds__(256, 3) void k_attn(const ushort* __restrict__ qi,
                                                 const ushort* __restrict__ ki,
                                                 const ushort* __restrict__ vti,
                                                 float* __restrict__ out) {
  __shared__ __align__(16) ushort Kb[2][64 * 64];
  __shared__ __align__(16) ushort Vb[2][64 * 64];

  const int f = blockIdx.x;
  const int g = f >> 8, r_ = f & 255;
  const int qt = ((r_ & 7) + g * 3) & 7;        // bijective, breaks 256-stride alignment
  const int bh = g * 32 + (r_ >> 3);
  const int b = bh / 12, h = bh % 12;
  const int w = threadIdx.x >> 6, lane = threadIdx.x & 63;
  const int ql = lane & 31, hi = lane >> 5;
  const int q0 = qt * 128 + w * 32;
  const int nt = (q0 >> 6) + 1;                 // this wave's kv-tile count
  const int ntmax = 2 * qt + 2;                 // block's kv-tile count
  const ushort* qb = qi  + (size_t)bh * SQ * DH;
  const ushort* kb = ki  + (size_t)bh * SQ * DH;
  const ushort* vb = vti + (size_t)bh * DH * SQ;

  short8 qf[4];
  #pragma unroll
  for (int m = 0; m < 4; ++m)
    qf[m] = *reinterpret_cast<const short8*>(qb + (size_t)(q0 + ql) * DH + m * 16 + hi * 8);

  f32x16 o0, o1;
  #pragma unroll
  for (int r = 0; r < 16; ++r) { o0[r] = 0.f; o1[r] = 0.f; }
  float m_run = -1e30f, l_run = 0.f;

#define STAGE(bufi, tt) do {                                                                   \
    const int kv0_ = (tt) * 64;                                                                \
    const int t0 = threadIdx.x, t1 = threadIdx.x + 256;                                        \
    gload_lds16(kb + (size_t)(kv0_ + (t0 >> 3)) * DH + (((t0 & 7) ^ ((t0 >> 3) & 7)) * 8),     \
                &Kb[bufi][0] + t0 * 8);                                                        \
    gload_lds16(kb + (size_t)(kv0_ + (t1 >> 3)) * DH + (((t1 & 7) ^ ((t1 >> 3) & 7)) * 8),     \
                &Kb[bufi][0] + t1 * 8);                                                        \
    gload_lds16(vb + (size_t)(t0 >> 3) * SQ + kv0_ + (((t0 & 7) ^ ((t0 >> 3) & 7)) * 8),       \
                &Vb[bufi][0] + t0 * 8);                                                        \
    gload_lds16(vb + (size_t)(t1 >> 3) * SQ + kv0_ + (((t1 & 7) ^ ((t1 >> 3) & 7)) * 8),       \
                &Vb[bufi][0] + t1 * 8);                                                        \
  } while (0)

  STAGE(0, 0);
  __syncthreads();

  int cur = 0;
  #pragma unroll 1
  for (int t = 0; t < ntmax; ++t) {
    if (t + 1 < ntmax) STAGE(cur ^ 1, t + 1);

    if (t < nt) {
      const int kv0 = t * 64;
      const ushort* Kc = &Kb[cur][0];
      const ushort* Vc = &Vb[cur][0];

      f32x16 s0, s1;
      #pragma unroll
      for (int r = 0; r < 16; ++r) { s0[r] = 0.f; s1[r] = 0.f; }
      #pragma unroll
      for (int m = 0; m < 4; ++m) {
        short8 kf = *reinterpret_cast<const short8*>(Kc + ql * 64 + ((2 * m + hi) ^ (ql & 7)) * 8);
        s0 = __builtin_amdgcn_mfma_f32_32x32x16_bf16(kf, qf[m], s0, 0, 0, 0);
      }
      #pragma unroll
      for (int m = 0; m < 4; ++m) {
        short8 kf = *reinterpret_cast<const short8*>(Kc + (32 + ql) * 64 + ((2 * m + hi) ^ (ql & 7)) * 8);
        s1 = __builtin_amdgcn_mfma_f32_32x32x16_bf16(kf, qf[m], s1, 0, 0, 0);
      }

      if (t == nt - 1) {
        const int qg = q0 + ql;
        #pragma unroll
        for (int r = 0; r < 16; ++r) {
          int kvl = (r & 3) + 8 * (r >> 2) + 4 * hi;
          if (kv0 + kvl      > qg) s0[r] = -1e30f;
          if (kv0 + 32 + kvl > qg) s1[r] = -1e30f;
        }
      }

      float mt = s0[0];
      #pragma unroll
      for (int r = 1; r < 16; ++r) mt = fmaxf(mt, s0[r]);
      #pragma unroll
      for (int r = 0; r < 16; ++r) mt = fmaxf(mt, s1[r]);
      mt = fmaxf(mt, __shfl_xor(mt, 32));
      if (__any(mt > m_run + 40.0f)) {
        float mnew = fmaxf(m_run, mt);
        float corr = exp2f((m_run - mnew) * SCL2);
        l_run *= corr; m_run = mnew;
        #pragma unroll
        for (int r = 0; r < 16; ++r) {
          float cr = __shfl(corr, (r & 3) + 8 * (r >> 2) + 4 * hi);
          o0[r] *= cr; o1[r] *= cr;
        }
      }
      float ts = 0.f;
      #pragma unroll
      for (int r = 0; r < 16; ++r) {
        s0[r] = exp2f((s0[r] - m_run) * SCL2); ts += s0[r];
        s1[r] = exp2f((s1[r] - m_run) * SCL2); ts += s1[r];
      }
      ts += __shfl_xor(ts, 32);
      l_run += ts;

#define PV_CHUNK(SV, CC, KC) do {                                                              \
        unsigned wa = cvtpk(SV[(CC) * 8 + 0], SV[(CC) * 8 + 1]);                               \
        unsigned wb = cvtpk(SV[(CC) * 8 + 2], SV[(CC) * 8 + 3]);                               \
        unsigned wc = cvtpk(SV[(CC) * 8 + 4], SV[(CC) * 8 + 5]);                               \
        unsigned wd = cvtpk(SV[(CC) * 8 + 6], SV[(CC) * 8 + 7]);                               \
        unsigned xa = __shfl_xor(wa, 32), xb2 = __shfl_xor(wb, 32);                            \
        unsigned xc = __shfl_xor(wc, 32), xd = __shfl_xor(wd, 32);                             \
        uint4 pw;                                                                              \
        pw.x = hi ? xc : wa;  pw.y = hi ? xd : wb;                                             \
        pw.z = hi ? wc : xa;  pw.w = hi ? wd : xb2;                                            \
        short8 pa = *reinterpret_cast<short8*>(&pw);                                           \
        short8 vf0 = *reinterpret_cast<const short8*>(Vc + ql * 64 +                           \
                       ((2 * (KC) + hi) ^ (ql & 7)) * 8);                                      \
        o0 = __builtin_amdgcn_mfma_f32_32x32x16_bf16(pa, vf0, o0, 0, 0, 0);                    \
        short8 vf1 = *reinterpret_cast<const short8*>(Vc + (32 + ql) * 64 +                    \
                       ((2 * (KC) + hi) ^ (ql & 7)) * 8);                                      \
        o1 = __builtin_amdgcn_mfma_f32_32x32x16_bf16(pa, vf1, o1, 0, 0, 0);                    \
      } while (0)

      PV_CHUNK(s0, 0, 0);
      PV_CHUNK(s0, 1, 1);
      PV_CHUNK(s1, 0, 2);
      PV_CHUNK(s1, 1, 3);
#undef PV_CHUNK
    }

    __syncthreads();
    cur ^= 1;
  }
#undef STAGE

  float rl = 1.0f / l_run;
  #pragma unroll
  for (int r = 0; r < 16; ++r) {
    int base = (r & 3) + 8 * (r >> 2) + 4 * hi;
    float sc_ = __shfl(rl, base);
    int qg = q0 + base;
    float* op = out + ((size_t)b * SQ + qg) * (NH * DH) + h * DH;
    op[ql]      = o0[r] * sc_;
    op[32 + ql] = o1[r] * sc_;
  }
}

extern "C" void kernel_launch(void* const* d_in, const int* in_sizes, int n_in,
                              void* d_out, int out_size, void* d_ws, size_t ws_size,
                              hipStream_t stream) {
  const float* x  = (const float*)d_in[0];
  const float* Wq = (const float*)d_in[1];
  const float* Wk = (const float*)d_in[2];
  const float* Wv = (const float*)d_in[3];
  float* out = (float*)d_out;

  char* ws = (char*)d_ws;
  ushort* xb = (ushort*)(ws);
  ushort* wt = (ushort*)(ws + 12582912);
  ushort* q  = (ushort*)(ws + 16121856);
  ushort* k  = (ushort*)(ws + 28704768);
  ushort* vt = (ushort*)(ws + 41287680);

  k_convert_x<<<3072, 256, 0, stream>>>(x, xb);
  k_prep_w<<<dim3(36, 12), 256, 0, stream>>>(Wq, Wk, Wv, wt);
  k_proj<<<dim3(64, 18), 256, 0, stream>>>(xb, wt, q, k, vt);
  k_attn<<<768, 256, 0, stream>>>(q, k, vt, out);
}